// Round 1
// baseline (356.518 us; speedup 1.0000x reference)
//
#include <hip/hip_runtime.h>
#include <math.h>
#include <cstdint>
#include <cstddef>

// ---------------------------------------------------------------------------
// Transformer-XL relative multihead attention, MI355X (gfx950)
// S=1024, M=1024, T=2048, B=4, D=1024, H=16, DH=64
// R9: k_attn dual-pass key-split for occupancy balance. Each block runs two
//     passes of exactly 25 tiles total: pass0 = keys [0, k+9) of query tile k,
//     pass1 = keys [xe+9, 2xe+18) of query tile xe=7-k. Partial O (f16,
//     unnormalized) + partial l (f32) per pass; k_combine normalizes.
//     Partial buffers reuse dead cbf/posb/wrelT regions (no ws growth).
//     Everything else as R8 (ds_bpermute E-shift, ring R, prefetch, split-K
//     proj).
// ---------------------------------------------------------------------------

typedef _Float16 half_t;
typedef _Float16 half8 __attribute__((ext_vector_type(8)));
typedef _Float16 half4v __attribute__((ext_vector_type(4)));
typedef float f32x4 __attribute__((ext_vector_type(4)));

#define S_LEN 1024
#define M_LEN 1024
#define T_LEN 2048
#define BATCH 4
#define NHEAD 16

__device__ inline void async_copy16(const half_t* g, half_t* l) {
  __builtin_amdgcn_global_load_lds(
      (const __attribute__((address_space(1))) void*)g,
      (__attribute__((address_space(3))) void*)l, 16, 0, 0);
}

// ---------------- fused fp32 -> fp16 convert: mem | x | pos ----------------
__global__ __launch_bounds__(256) void k_convert3(const float* __restrict__ mem,
                                                  const float* __restrict__ x,
                                                  const float* __restrict__ pos,
                                                  half_t* __restrict__ cbf,
                                                  half_t* __restrict__ posb) {
  const int i = blockIdx.x * 256 + threadIdx.x;  // grid covers 2621440 float4s
  const float* src;
  half_t* dst;
  int off;
  if (i < 1048576)      { src = mem; dst = cbf;           off = i; }
  else if (i < 2097152) { src = x;   dst = cbf + 4194304; off = i - 1048576; }
  else                  { src = pos; dst = posb;          off = i - 2097152; }
  const float4 v = ((const float4*)src)[off];
  half4v h;
  h[0] = (half_t)v.x; h[1] = (half_t)v.y; h[2] = (half_t)v.z; h[3] = (half_t)v.w;
  ((half4v*)dst)[off] = h;
}

// ------- fused transpose+convert of the 3 weights: [1024][C] -> [C][1024] ----
__global__ __launch_bounds__(256) void k_transpose_w3(const float* __restrict__ Wqkv,
                                                      const float* __restrict__ Wrel,
                                                      const float* __restrict__ Wo,
                                                      half_t* __restrict__ wqkvT,
                                                      half_t* __restrict__ wrelT,
                                                      half_t* __restrict__ woT) {
  __shared__ float tile[64][65];
  const int y = blockIdx.y;
  const float* src; half_t* dst; int C, c0;
  if (y < 48)      { src = Wqkv; dst = wqkvT; C = 3072; c0 = y * 64; }
  else if (y < 64) { src = Wrel; dst = wrelT; C = 1024; c0 = (y - 48) * 64; }
  else             { src = Wo;   dst = woT;   C = 1024; c0 = (y - 64) * 64; }
  const int t = threadIdx.x;
  const int r0 = blockIdx.x * 64;
  const int tx = t & 63, ty4 = t >> 6;
#pragma unroll
  for (int k = 0; k < 16; ++k) {
    int row = k * 4 + ty4;
    tile[row][tx] = src[(size_t)(r0 + row) * C + c0 + tx];
  }
  __syncthreads();
#pragma unroll
  for (int k = 0; k < 16; ++k) {
    int orow = k * 4 + ty4;
    dst[(size_t)(c0 + orow) * 1024 + r0 + tx] = (half_t)tile[tx][orow];
  }
}

// ---------------- fp16 GEMM core (m97 structure + XOR-swizzled LDS) --------
// ld = row stride of A and B (K-dim may be a sub-range for split-K).
__device__ inline void gemm_body(const half_t* __restrict__ A,
                                 const half_t* __restrict__ B,
                                 half_t* __restrict__ C,
                                 int N, int K, int ld, int m0, int n0,
                                 half_t (*ldsA)[64], half_t (*ldsB)[64]) {
  const int t = threadIdx.x;
  const int wave = t >> 6, lane = t & 63, quad = lane >> 4, l15 = lane & 15;
  const int wm = (wave >> 1) * 64, wn = (wave & 1) * 64;
  const int srow = lane >> 3;
  const int scol = ((lane & 7) ^ srow) * 8;  // XOR'd global source chunk
  f32x4 acc[4][4] = {};
  for (int k0 = 0; k0 < K; k0 += 64) {
    __syncthreads();
#pragma unroll
    for (int i = 0; i < 4; ++i) {
      const int r0 = (wave * 4 + i) * 8;
      async_copy16(&A[(size_t)(m0 + r0 + srow) * ld + k0 + scol], &ldsA[r0][0]);
      async_copy16(&B[(size_t)(n0 + r0 + srow) * ld + k0 + scol], &ldsB[r0][0]);
    }
    __syncthreads();
#pragma unroll
    for (int ks = 0; ks < 2; ++ks) {
      half8 af[4], bf[4];
#pragma unroll
      for (int mt = 0; mt < 4; ++mt)
        af[mt] = *(const half8*)&ldsA[wm + mt * 16 + l15][((ks * 4 + quad) ^ (l15 & 7)) * 8];
#pragma unroll
      for (int nt = 0; nt < 4; ++nt)
        bf[nt] = *(const half8*)&ldsB[wn + nt * 16 + l15][((ks * 4 + quad) ^ (l15 & 7)) * 8];
#pragma unroll
      for (int mt = 0; mt < 4; ++mt)
#pragma unroll
        for (int nt = 0; nt < 4; ++nt)
          acc[mt][nt] = __builtin_amdgcn_mfma_f32_16x16x32_f16(af[mt], bf[nt], acc[mt][nt], 0, 0, 0);
    }
  }
#pragma unroll
  for (int mt = 0; mt < 4; ++mt)
#pragma unroll
    for (int nt = 0; nt < 4; ++nt)
#pragma unroll
      for (int r = 0; r < 4; ++r) {
        const int row = m0 + wm + mt * 16 + quad * 4 + r;
        const int col = n0 + wn + nt * 16 + l15;
        C[(size_t)row * N + col] = (half_t)acc[mt][nt][r];
      }
}

// fused qkv (1536 blocks) + pos (128 blocks) GEMM, K=1024 both
__global__ __launch_bounds__(256) void k_gemm_qkv_pos(const half_t* __restrict__ cbf,
                                                      const half_t* __restrict__ wqkvT,
                                                      half_t* __restrict__ qkv,
                                                      const half_t* __restrict__ posb,
                                                      const half_t* __restrict__ wrelT,
                                                      half_t* __restrict__ rb) {
  __shared__ half_t ldsA[128][64];
  __shared__ half_t ldsB[128][64];
  const int bid = blockIdx.x;
  if (bid < 1536)
    gemm_body(cbf, wqkvT, qkv, 3072, 1024, 1024, (bid & 63) * 128, (bid >> 6) * 128, ldsA, ldsB);
  else {
    const int b2 = bid - 1536;
    gemm_body(posb, wrelT, rb, 1024, 1024, 1024, (b2 & 15) * 128, (b2 >> 4) * 128, ldsA, ldsB);
  }
}

// proj GEMM, split-K=2: halves write fp16 partials summed in k_ln.
__global__ __launch_bounds__(256) void k_gemm_proj(const half_t* __restrict__ av,
                                                   const half_t* __restrict__ woT,
                                                   half_t* __restrict__ out0,
                                                   half_t* __restrict__ out1) {
  __shared__ half_t ldsA[128][64];
  __shared__ half_t ldsB[128][64];
  const int bid = blockIdx.x;
  const int h = bid >> 8, b2 = bid & 255;
  gemm_body(av + h * 512, woT + h * 512, h ? out1 : out0,
            1024, 512, 1024, (b2 & 31) * 128, (b2 >> 5) * 128, ldsA, ldsB);
}

// ---------------- V transpose: qkv v-slice -> vT[(b*16+n)*64+dh][T] ----------
__global__ __launch_bounds__(256) void k_transpose_v(const half_t* __restrict__ qkv,
                                                     half_t* __restrict__ vT) {
  __shared__ half_t tile[64][72];
  const int t = threadIdx.x;
  const int t0 = blockIdx.x * 64, bn = blockIdx.y, b = bn >> 4, n = bn & 15;
#pragma unroll
  for (int i = 0; i < 2; ++i) {
    const int ci = t + i * 256;
    const int row = ci >> 3, co = (ci & 7) * 8;
    *(half8*)&tile[row][co] =
        *(const half8*)&qkv[((size_t)(t0 + row) * BATCH + b) * 3072 + 2048 + n * 64 + co];
  }
  __syncthreads();
#pragma unroll
  for (int i = 0; i < 2; ++i) {
    const int ci = t + i * 256;
    const int dh = ci >> 3, to = (ci & 7) * 8;
    half8 v;
#pragma unroll
    for (int j = 0; j < 8; ++j) v[j] = tile[to + j][dh];
    *(half8*)&vT[((size_t)bn * 64 + dh) * 2048 + t0 + to] = v;
  }
}

// ---------------- flash attention with Transformer-XL relative shift --------
// 512 threads = 8 waves; block owns 128 queries per pass. Dual-pass key-split:
// pass0 = query tile k, keys [0, (k+9)*64); pass1 = query tile 7-k, keys
// [(xe+9)*64, (2xe+18)*64). Every block = exactly 25 tiles (balanced).
// Unnormalized f16 O-partials + f32 l-partials; k_combine normalizes.
__global__ __launch_bounds__(512, 4) void k_attn(const half_t* __restrict__ qkv,
                                                 const half_t* __restrict__ rbuf,
                                                 const half_t* __restrict__ vT,
                                                 const float* __restrict__ pbu,
                                                 const float* __restrict__ pbv,
                                                 half_t* __restrict__ av0,
                                                 half_t* __restrict__ av1,
                                                 float* __restrict__ lsum) {
  __shared__ __align__(16) half_t ldsK[64][64];        // [key][dh], XOR chunks
  __shared__ __align__(16) half_t ldsV[64][64];        // [dh][key], XOR chunks
  __shared__ __align__(16) half_t ldsR[256][64];       // r ring, XOR chunks
  __shared__ __align__(16) half_t ldsP[8][16][72];     // per-wave P (wave-internal)
  const int t = threadIdx.x;
  const int wave = t >> 6, lane = t & 63, quad = lane >> 4, l15 = lane & 15;

  const int li = blockIdx.x + 8 * blockIdx.y;   // 0..511
  const int kq = li & 7;                        // block's query-tile index
  const int bn = li >> 3;
  const int b = bn >> 4, n = bn & 15;

  // E-shift lane rotation constants (pass-invariant): score col cj reads
  // window col cj + 15 - irow; rotation is uniform within a quad per r.
  int bperm_idx[4];
  bool lo_sel[4];
#pragma unroll
  for (int r = 0; r < 4; ++r) {
    const int irow = quad * 4 + r;
    bperm_idx[r] = ((lane & 48) | ((l15 + 15 - irow) & 15)) << 2;
    lo_sel[r] = (l15 <= irow);  // true: window col in tile nt; false: nt+1
  }

  const float k1 = 0.125f * 1.44269504088896f;  // scale * log2(e)
  const float kC = -4.0f * 1.44269504088896f;   // -C * log2(e)

  // staging geometry (K/V and steady-state R: 512 thr cover 64 rows x 8 chunks)
  const int srow = t >> 3, sc3 = t & 7;
  const int sxk = (sc3 ^ (srow & 7)) * 8;

  for (int pass = 0; pass < 2; ++pass) {
    const int xe = pass ? 7 - kq : kq;
    const int i0 = xe * 128;
    const int i_base = i0 + wave * 16;
    const int p0 = 896 - i0;             // global r-row of ring origin at tile 0
    const int kt0 = pass ? xe + 9 : 0;
    const int kt1 = pass ? 2 * xe + 18 : xe + 9;

    // q fragments with biases folded in
    half8 qu[2], qv[2];
#pragma unroll
    for (int ks = 0; ks < 2; ++ks) {
      const int dh0 = ks * 32 + quad * 8;
      const half8 qf = *(const half8*)&qkv[((size_t)(M_LEN + i_base + l15) * BATCH + b) * 3072 + n * 64 + dh0];
#pragma unroll
      for (int j = 0; j < 8; ++j) {
        const float qj = (float)qf[j];
        qu[ks][j] = (half_t)(qj + pbu[n * 64 + dh0 + j]);
        qv[ks][j] = (half_t)(qj + pbv[n * 64 + dh0 + j]);
      }
    }

    f32x4 oacc[4] = {};
    float lpart[4] = {0.f, 0.f, 0.f, 0.f};

    // ---- prologue: K/V tile kt0, R ring rows [jb+p0, jb+p0+255] ----
    const int jb = kt0 * 64;
    half8 kreg = *(const half8*)&qkv[((size_t)(jb + srow) * BATCH + b) * 3072 + 1024 + n * 64 + sc3 * 8];
    half8 vreg = *(const half8*)&vT[((size_t)bn * 64 + srow) * 2048 + jb + sc3 * 8];
    half8 rreg4[4];
    int rr4[4], rc4[4];
#pragma unroll
    for (int i = 0; i < 4; ++i) {
      const int ci = t + 512 * i;
      rr4[i] = ci >> 3; rc4[i] = ci & 7;
      const int pg = p0 + jb + rr4[i];
      const int ps = pg > 2047 ? 2047 : pg;
      rreg4[i] = *(const half8*)&rbuf[(size_t)ps * 1024 + n * 64 + rc4[i] * 8];
    }
    half8 rpre;  // steady-state prefetch reg

    for (int kt = kt0; kt < kt1; ++kt) {
      const int j0 = kt * 64;

      __syncthreads();  // prev-iter LDS reads done; drains vmcnt -> regs ready
      *(half8*)&ldsK[srow][sxk] = kreg;
      *(half8*)&ldsV[srow][sxk] = vreg;
      if (kt == kt0) {
#pragma unroll
        for (int i = 0; i < 4; ++i) {
          const int pg = p0 + jb + rr4[i];
          *(half8*)&ldsR[pg & 255][(rc4[i] ^ (pg & 7)) * 8] = rreg4[i];
        }
      } else {
        const int pw = j0 + p0 + 192 + srow;  // rows loaded during tile kt-1
        *(half8*)&ldsR[pw & 255][(sc3 ^ (pw & 7)) * 8] = rpre;
      }
      __syncthreads();

      // ---- prefetch tile kt+1 (regs dead after the writes above) ----
      if (kt + 1 < kt1) {
        const int j0n = j0 + 64;
        kreg = *(const half8*)&qkv[((size_t)(j0n + srow) * BATCH + b) * 3072 + 1024 + n * 64 + sc3 * 8];
        vreg = *(const half8*)&vT[((size_t)bn * 64 + srow) * 2048 + j0n + sc3 * 8];
        const int pn = j0 + p0 + 256 + srow;  // new ring rows for tile kt+1
        const int pc = pn > 2047 ? 2047 : pn;
        rpre = *(const half8*)&rbuf[(size_t)pc * 1024 + n * 64 + sc3 * 8];
      }

      // ---- AC = (q+u) @ K^T ----
      f32x4 ac[4] = {};
#pragma unroll
      for (int ks = 0; ks < 2; ++ks)
#pragma unroll
        for (int nt = 0; nt < 4; ++nt) {
          const int row = nt * 16 + l15;
          const half8 kf = *(const half8*)&ldsK[row][((ks * 4 + quad) ^ (row & 7)) * 8];
          ac[nt] = __builtin_amdgcn_mfma_f32_16x16x32_f16(qu[ks], kf, ac[nt], 0, 0, 0);
        }

      // ---- E window: E[m][c] = (q+v) . r[window c], width 80 (ring reads) ----
      const int rbg = j0 + p0 + 112 - wave * 16;  // wave's window start (global)
      f32x4 ea[5] = {};
#pragma unroll
      for (int ks = 0; ks < 2; ++ks)
#pragma unroll
        for (int et = 0; et < 5; ++et) {
          const int pr = rbg + et * 16 + l15;
          const half8 rf = *(const half8*)&ldsR[pr & 255][((ks * 4 + quad) ^ (pr & 7)) * 8];
          ea[et] = __builtin_amdgcn_mfma_f32_16x16x32_f16(qv[ks], rf, ea[et], 0, 0, 0);
        }

      // ---- scores -> p; E shift via in-register bpermute (f32) ----
      const bool maskt = j0 > i_base + 960;
#pragma unroll
      for (int r = 0; r < 4; ++r) {
        const int irow = quad * 4 + r;
        const int ig = i_base + irow;
        float rot[5];
#pragma unroll
        for (int et = 0; et < 5; ++et)
          rot[et] = __int_as_float(
              __builtin_amdgcn_ds_bpermute(bperm_idx[r], __float_as_int(ea[et][r])));
        float psum = 0.f;
#pragma unroll
        for (int nt = 0; nt < 4; ++nt) {
          const float ev = lo_sel[r] ? rot[nt] : rot[nt + 1];
          const int cj = nt * 16 + l15;
          float p = __builtin_amdgcn_exp2f(fmaf(ac[nt][r] + ev, k1, kC));
          if (maskt && (j0 + cj > ig + M_LEN)) p = 0.f;
          psum += p;
          ldsP[wave][irow][cj] = (half_t)p;
        }
        lpart[r] += psum;
      }
      __builtin_amdgcn_wave_barrier();  // P round trip is wave-internal

      // ---- PV ----
      half8 pa[2];
#pragma unroll
      for (int ks = 0; ks < 2; ++ks)
        pa[ks] = *(const half8*)&ldsP[wave][l15][ks * 32 + quad * 8];
#pragma unroll
      for (int ks = 0; ks < 2; ++ks)
#pragma unroll
        for (int dnt = 0; dnt < 4; ++dnt) {
          const int row = dnt * 16 + l15;
          const half8 vf = *(const half8*)&ldsV[row][((ks * 4 + quad) ^ (row & 7)) * 8];
          oacc[dnt] = __builtin_amdgcn_mfma_f32_16x16x32_f16(pa[ks], vf, oacc[dnt], 0, 0, 0);
        }
    }

    // ---- per-pass epilogue: unnormalized O-partial (f16) + l-partial ----
    half_t* __restrict__ avh = pass ? av1 : av0;
    float* __restrict__ lb = lsum + (pass ? 65536 : 0);
#pragma unroll
    for (int r = 0; r < 4; ++r) {
      float l = lpart[r];
#pragma unroll
      for (int off = 1; off < 16; off <<= 1) l += __shfl_xor(l, off);
      const int ig = i_base + quad * 4 + r;
#pragma unroll
      for (int dnt = 0; dnt < 4; ++dnt)
        avh[((size_t)ig * BATCH + b) * 1024 + n * 64 + dnt * 16 + l15] = (half_t)oacc[dnt][r];
      if (l15 == 0) lb[((size_t)ig * BATCH + b) * 16 + n] = l;
    }
  }
}

// -------- combine the two key-split halves: av = (av0+av1)/(l0+l1) ----------
__global__ __launch_bounds__(256) void k_combine(const half_t* __restrict__ a0,
                                                 const half_t* __restrict__ a1,
                                                 const float* __restrict__ lsum,
                                                 half_t* __restrict__ av) {
  const int row = blockIdx.x;          // 4096 = (ig, b)
  const int t = threadIdx.x;           // 256 threads x 4 halves = 1024 cols
  const int n = t >> 4;                // (t*4) >> 6
  const float inv = 1.f / (lsum[row * 16 + n] + lsum[65536 + row * 16 + n]);
  const half4v x0 = ((const half4v*)(a0 + (size_t)row * 1024))[t];
  const half4v x1 = ((const half4v*)(a1 + (size_t)row * 1024))[t];
  half4v o;
#pragma unroll
  for (int j = 0; j < 4; ++j) o[j] = (half_t)(((float)x0[j] + (float)x1[j]) * inv);
  ((half4v*)(av + (size_t)row * 1024))[t] = o;
}

// -------- residual + LayerNorm (one block per row; sums 2 fp16 partials) ----
__global__ __launch_bounds__(256) void k_ln(const float* __restrict__ x,
                                            const half_t* __restrict__ ao0,
                                            const half_t* __restrict__ ao1,
                                            const float* __restrict__ gamma,
                                            const float* __restrict__ beta,
                                            float* __restrict__ out) {
  const int row = blockIdx.x;
  const int t = threadIdx.x;
  const float4 xv = ((const float4*)(x + (size_t)row * 1024))[t];
  const half4v a4 = ((const half4v*)(ao0 + (size_t)row * 1024))[t];
  const half4v b4 = ((const half4v*)(ao1 + (size_t)row * 1024))[t];
  const float y0 = xv.x + (float)a4[0] + (float)b4[0];
  const float y1 = xv.y + (float)a4[1] + (float)b4[1];
  const float y2 = xv.z + (float)a4[2] + (float)b4[2];
  const float y3 = xv.w + (float)a4[3] + (float)b4[3];
  float s = y0 + y1 + y2 + y3;
  float ss = y0 * y0 + y1 * y1 + y2 * y2 + y3 * y3;
#pragma unroll
  for (int off = 1; off < 64; off <<= 1) {
    s += __shfl_xor(s, off);
    ss += __shfl_xor(ss, off);
  }
  __shared__ float sb[4], ssb[4];
  if ((t & 63) == 0) { sb[t >> 6] = s; ssb[t >> 6] = ss; }
  __syncthreads();
  s = sb[0] + sb[1] + sb[2] + sb[3];
  ss = ssb[0] + ssb[1] + ssb[2] + ssb[3];
  const float mean = s * (1.f / 1024.f);
  const float var = ss * (1.f / 1024.f) - mean * mean;
  const float rstd = rsqrtf(var + 1e-5f);
  const float4 g = ((const float4*)gamma)[t];
  const float4 be = ((const float4*)beta)[t];
  float4 o;
  o.x = (y0 - mean) * rstd * g.x + be.x;
  o.y = (y1 - mean) * rstd * g.y + be.y;
  o.z = (y2 - mean) * rstd * g.z + be.z;
  o.w = (y3 - mean) * rstd * g.w + be.w;
  ((float4*)(out + (size_t)row * 1024))[t] = o;
}

// ---------------------------------------------------------------------------
extern "C" void kernel_launch(void* const* d_in, const int* in_sizes, int n_in,
                              void* d_out, int out_size, void* d_ws, size_t ws_size,
                              hipStream_t stream) {
  const float* x     = (const float*)d_in[0];
  const float* pos   = (const float*)d_in[1];
  const float* pbu   = (const float*)d_in[2];
  const float* pbv   = (const float*)d_in[3];
  const float* mem   = (const float*)d_in[4];
  const float* Wqkv  = (const float*)d_in[5];
  const float* Wrel  = (const float*)d_in[6];
  const float* Wo    = (const float*)d_in[7];
  const float* gamma = (const float*)d_in[8];
  const float* beta  = (const float*)d_in[9];
  float* out = (float*)d_out;

  half_t* ws    = (half_t*)d_ws;
  half_t* cbf   = ws;                 // [8192][1024]
  half_t* posb  = cbf + 8388608;      // [2048][1024]
  half_t* wqkvT = posb + 2097152;     // [3072][1024]
  half_t* wrelT = wqkvT + 3145728;    // [1024][1024]
  half_t* woT   = wrelT + 1048576;    // [1024][1024]
  half_t* qkv   = woT + 1048576;      // [8192][3072]
  half_t* rb    = qkv + 25165824;     // [2048][1024]
  half_t* vT    = rb + 2097152;       // [64][64][2048]
  half_t* av    = vT + 8388608;       // [4096][1024]
  half_t* aout0 = qkv;                // reuse qkv region (partial 0)
  half_t* aout1 = qkv + 4194304;      // partial 1
  // key-split partials reuse regions dead after k_gemm_qkv_pos:
  half_t* av0c  = cbf;                // [4096][1024] f16 (fits in cbf)
  half_t* av1c  = posb;               // [4096][1024] f16 (posb+wqkvT space)
  float*  lsum  = (float*)wrelT;      // [2][4096][16] f32 (fits in wrelT)

  k_convert3<<<10240, 256, 0, stream>>>(mem, x, pos, cbf, posb);
  k_transpose_w3<<<dim3(16, 80), 256, 0, stream>>>(Wqkv, Wrel, Wo, wqkvT, wrelT, woT);
  k_gemm_qkv_pos<<<1664, 256, 0, stream>>>(cbf, wqkvT, qkv, posb, wrelT, rb);
  k_transpose_v<<<dim3(32, 64), 256, 0, stream>>>(qkv, vT);
  k_attn<<<dim3(8, 64), 512, 0, stream>>>(qkv, rb, vT, pbu, pbv, av0c, av1c, lsum);
  k_combine<<<4096, 256, 0, stream>>>(av0c, av1c, lsum, av);
  k_gemm_proj<<<512, 256, 0, stream>>>(av, woT, aout0, aout1);
  k_ln<<<4096, 256, 0, stream>>>(x, aout0, aout1, gamma, beta, out);
}